// Round 1
// baseline (397.086 us; speedup 1.0000x reference)
//
#include <hip/hip_runtime.h>
#include <hip/hip_bf16.h>
#include <math.h>

#define DIM 1024
#define HID 2048
#define NE  4
#define NT  4096            // B*T tokens
#define KW  (NE*HID)        // 8192, GEMM2 K / Hw leading dim

typedef __attribute__((ext_vector_type(8))) short short8;
typedef __attribute__((ext_vector_type(4))) short short4v;
typedef __attribute__((ext_vector_type(4))) float floatx4;

// ---- helpers ----------------------------------------------------------------

__device__ __forceinline__ void async_cp16(const void* g, void* l) {
  __builtin_amdgcn_global_load_lds(
      (const __attribute__((address_space(1))) void*)g,
      (__attribute__((address_space(3))) void*)l, 16, 0, 0);
}

__device__ __forceinline__ short f2bf(float f) {
  union { float f; unsigned u; } x; x.f = f;
  unsigned r = x.u + 0x7fffu + ((x.u >> 16) & 1u);   // round-to-nearest-even
  return (short)(r >> 16);
}

// ---- router: weights = softmax(x @ Wr + br), fp32 exact ---------------------
// one wave per token; 4 dot-products of length 1024 reduced across the wave
__global__ void router_kernel(const float* __restrict__ x,
                              const float* __restrict__ Wr,
                              const float* __restrict__ br,
                              float* __restrict__ wgt) {
  const int wv = threadIdx.x >> 6, lane = threadIdx.x & 63;
  const int t = blockIdx.x * 4 + wv;
  const float* xr = x + (size_t)t * DIM;
  float a0 = 0.f, a1 = 0.f, a2 = 0.f, a3 = 0.f;
  for (int d = lane; d < DIM; d += 64) {
    float xv = xr[d];
    floatx4 wr = *(const floatx4*)&Wr[d * 4];
    a0 += xv * wr[0]; a1 += xv * wr[1]; a2 += xv * wr[2]; a3 += xv * wr[3];
  }
  #pragma unroll
  for (int off = 32; off; off >>= 1) {
    a0 += __shfl_down(a0, off);
    a1 += __shfl_down(a1, off);
    a2 += __shfl_down(a2, off);
    a3 += __shfl_down(a3, off);
  }
  a0 = __shfl(a0, 0); a1 = __shfl(a1, 0); a2 = __shfl(a2, 0); a3 = __shfl(a3, 0);
  float s0 = a0 + br[0], s1 = a1 + br[1], s2 = a2 + br[2], s3 = a3 + br[3];
  float m = fmaxf(fmaxf(s0, s1), fmaxf(s2, s3));
  float e0 = __expf(s0 - m), e1 = __expf(s1 - m), e2 = __expf(s2 - m), e3 = __expf(s3 - m);
  float inv = 1.f / (e0 + e1 + e2 + e3);
  float v = (lane == 0) ? e0 : (lane == 1) ? e1 : (lane == 2) ? e2 : e3;
  if (lane < 4) wgt[t * 4 + lane] = v * inv;
}

// ---- x: fp32 -> bf16, vectorized -------------------------------------------
__global__ void cvt_x(const float* __restrict__ x, short* __restrict__ xb) {
  int i = (blockIdx.x * 256 + threadIdx.x) * 4;
  floatx4 v = *(const floatx4*)&x[i];
  short4v o;
  o[0] = f2bf(v[0]); o[1] = f2bf(v[1]); o[2] = f2bf(v[2]); o[3] = f2bf(v[3]);
  *(short4v*)&xb[i] = o;
}

// ---- fp32 [z][R][C] -> bf16 [z][C][R] transpose+convert ---------------------
__global__ void transpose_cvt(const float* __restrict__ in, short* __restrict__ out,
                              int R, int C) {
  __shared__ float tile[32][33];
  const size_t zo = (size_t)blockIdx.z * R * C;
  in += zo; out += zo;
  const int tx = threadIdx.x, ty = threadIdx.y;   // 32 x 8
  const int c = blockIdx.x * 32 + tx;
  #pragma unroll
  for (int i = 0; i < 4; i++) {
    int r = blockIdx.y * 32 + ty + i * 8;
    tile[ty + i * 8][tx] = in[(size_t)r * C + c];
  }
  __syncthreads();
  const int r2 = blockIdx.y * 32 + tx;            // output minor index (= input row)
  #pragma unroll
  for (int i = 0; i < 4; i++) {
    int c2 = blockIdx.x * 32 + ty + i * 8;        // output major index (= input col)
    out[(size_t)c2 * R + r2] = f2bf(tile[tx][ty + i * 8]);
  }
}

// ---- GEMM1: Hw[t][e*HID+h] = bf16( w[t][e] * gelu(x @ W1[e] + b1[e]) ) ------
// A = xb [NT][DIM] bf16, B^T = w1t[e] [HID][DIM] bf16. 128x128 tile, BK=32.
__global__ __launch_bounds__(256, 2)
void gemm1_kernel(const short* __restrict__ xb, const short* __restrict__ w1t,
                  const float* __restrict__ b1, const float* __restrict__ wgt,
                  short* __restrict__ hw) {
  const int e  = blockIdx.z;
  const int m0 = blockIdx.y * 128;
  const int n0 = blockIdx.x * 128;
  const int tid = threadIdx.x;
  const int lane = tid & 63;
  const int wv = tid >> 6;
  const int wm = (wv >> 1) * 64, wn = (wv & 1) * 64;
  const int quad = lane >> 4, lrow = lane & 15;
  const int srow = tid >> 2;            // staging row 0..63
  const int skof = (tid & 3) * 8;       // staging k element offset

  __shared__ __align__(16) short As[128 * 32];
  __shared__ __align__(16) short Bs[128 * 32];

  const short* Ap = xb;
  const short* Bp = w1t + (size_t)e * HID * DIM;

  floatx4 acc[4][4];
  #pragma unroll
  for (int i = 0; i < 4; i++)
    #pragma unroll
    for (int j = 0; j < 4; j++) acc[i][j] = (floatx4)0.f;

  for (int k0 = 0; k0 < DIM; k0 += 32) {
    __syncthreads();
    async_cp16(Ap + (size_t)(m0 + srow)      * DIM + k0 + skof, As + tid * 8);
    async_cp16(Ap + (size_t)(m0 + 64 + srow) * DIM + k0 + skof, As + 2048 + tid * 8);
    async_cp16(Bp + (size_t)(n0 + srow)      * DIM + k0 + skof, Bs + tid * 8);
    async_cp16(Bp + (size_t)(n0 + 64 + srow) * DIM + k0 + skof, Bs + 2048 + tid * 8);
    __syncthreads();
    short8 af[4], bf[4];
    #pragma unroll
    for (int i = 0; i < 4; i++)
      af[i] = *(const short8*)&As[(wm + i * 16 + lrow) * 32 + quad * 8];
    #pragma unroll
    for (int j = 0; j < 4; j++)
      bf[j] = *(const short8*)&Bs[(wn + j * 16 + lrow) * 32 + quad * 8];
    #pragma unroll
    for (int i = 0; i < 4; i++)
      #pragma unroll
      for (int j = 0; j < 4; j++)
        acc[i][j] = __builtin_amdgcn_mfma_f32_16x16x32_bf16(af[i], bf[j], acc[i][j], 0, 0, 0);
  }

  // epilogue: bias + exact gelu + router-weight fold + bf16 store
  #pragma unroll
  for (int i = 0; i < 4; i++) {
    const int rbase = m0 + wm + i * 16 + quad * 4;
    float wv4[4];
    #pragma unroll
    for (int r = 0; r < 4; r++) wv4[r] = wgt[(rbase + r) * NE + e];
    #pragma unroll
    for (int j = 0; j < 4; j++) {
      const int col = n0 + wn + j * 16 + lrow;          // h
      const float b = b1[e * HID + col];
      #pragma unroll
      for (int r = 0; r < 4; r++) {
        float v = acc[i][j][r] + b;
        float g = 0.5f * v * (1.0f + erff(v * 0.70710678118f));
        hw[(size_t)(rbase + r) * KW + e * HID + col] = f2bf(wv4[r] * g);
      }
    }
  }
}

// ---- GEMM2: out[t][d] = Hw @ W2t^T + sum_e w[t][e]*b2[e][d] -----------------
// A = hw [NT][KW] bf16, B^T = w2t [DIM][KW] bf16.
__global__ __launch_bounds__(256, 2)
void gemm2_kernel(const short* __restrict__ hw, const short* __restrict__ w2t,
                  const float* __restrict__ b2, const float* __restrict__ wgt,
                  float* __restrict__ out) {
  const int m0 = blockIdx.y * 128;
  const int n0 = blockIdx.x * 128;
  const int tid = threadIdx.x;
  const int lane = tid & 63;
  const int wv = tid >> 6;
  const int wm = (wv >> 1) * 64, wn = (wv & 1) * 64;
  const int quad = lane >> 4, lrow = lane & 15;
  const int srow = tid >> 2;
  const int skof = (tid & 3) * 8;

  __shared__ __align__(16) short As[128 * 32];
  __shared__ __align__(16) short Bs[128 * 32];

  floatx4 acc[4][4];
  #pragma unroll
  for (int i = 0; i < 4; i++)
    #pragma unroll
    for (int j = 0; j < 4; j++) acc[i][j] = (floatx4)0.f;

  for (int k0 = 0; k0 < KW; k0 += 32) {
    __syncthreads();
    async_cp16(hw  + (size_t)(m0 + srow)      * KW + k0 + skof, As + tid * 8);
    async_cp16(hw  + (size_t)(m0 + 64 + srow) * KW + k0 + skof, As + 2048 + tid * 8);
    async_cp16(w2t + (size_t)(n0 + srow)      * KW + k0 + skof, Bs + tid * 8);
    async_cp16(w2t + (size_t)(n0 + 64 + srow) * KW + k0 + skof, Bs + 2048 + tid * 8);
    __syncthreads();
    short8 af[4], bf[4];
    #pragma unroll
    for (int i = 0; i < 4; i++)
      af[i] = *(const short8*)&As[(wm + i * 16 + lrow) * 32 + quad * 8];
    #pragma unroll
    for (int j = 0; j < 4; j++)
      bf[j] = *(const short8*)&Bs[(wn + j * 16 + lrow) * 32 + quad * 8];
    #pragma unroll
    for (int i = 0; i < 4; i++)
      #pragma unroll
      for (int j = 0; j < 4; j++)
        acc[i][j] = __builtin_amdgcn_mfma_f32_16x16x32_bf16(af[i], bf[j], acc[i][j], 0, 0, 0);
  }

  // epilogue: + sum_e w[t][e] * b2[e][d], fp32 store
  #pragma unroll
  for (int i = 0; i < 4; i++) {
    const int rbase = m0 + wm + i * 16 + quad * 4;
    floatx4 wr[4];
    #pragma unroll
    for (int r = 0; r < 4; r++) wr[r] = *(const floatx4*)&wgt[(rbase + r) * NE];
    #pragma unroll
    for (int j = 0; j < 4; j++) {
      const int col = n0 + wn + j * 16 + lrow;          // d
      float b2v[4];
      #pragma unroll
      for (int eI = 0; eI < 4; eI++) b2v[eI] = b2[eI * DIM + col];
      #pragma unroll
      for (int r = 0; r < 4; r++) {
        float bias = wr[r][0] * b2v[0] + wr[r][1] * b2v[1] +
                     wr[r][2] * b2v[2] + wr[r][3] * b2v[3];
        out[(size_t)(rbase + r) * DIM + col] = acc[i][j][r] + bias;
      }
    }
  }
}

// ---- launch -----------------------------------------------------------------

extern "C" void kernel_launch(void* const* d_in, const int* in_sizes, int n_in,
                              void* d_out, int out_size, void* d_ws, size_t ws_size,
                              hipStream_t stream) {
  const float* x  = (const float*)d_in[0];
  const float* W1 = (const float*)d_in[1];
  const float* b1 = (const float*)d_in[2];
  const float* W2 = (const float*)d_in[3];
  const float* b2 = (const float*)d_in[4];
  const float* Wr = (const float*)d_in[5];
  const float* br = (const float*)d_in[6];
  float* out = (float*)d_out;

  char* ws = (char*)d_ws;
  float* wgt = (float*)(ws);                      //   64 KB: [NT][NE] fp32
  short* xb  = (short*)(ws + 65536);              //    8 MB: [NT][DIM] bf16
  short* w1t = (short*)(ws + 8454144);            //   16 MB: [NE][HID][DIM] bf16
  short* w2t = (short*)(ws + 25231360);           //   16 MB: [DIM][KW] bf16
  short* hw  = (short*)(ws + 42008576);           //   64 MB: [NT][KW] bf16

  hipLaunchKernelGGL(router_kernel, dim3(NT / 4), dim3(256), 0, stream, x, Wr, br, wgt);
  hipLaunchKernelGGL(cvt_x, dim3(NT * DIM / 1024), dim3(256), 0, stream, x, xb);
  hipLaunchKernelGGL(transpose_cvt, dim3(HID / 32, DIM / 32, NE), dim3(32, 8), 0, stream,
                     W1, w1t, DIM, HID);
  hipLaunchKernelGGL(transpose_cvt, dim3(DIM / 32, KW / 32, 1), dim3(32, 8), 0, stream,
                     W2, w2t, KW, DIM);
  hipLaunchKernelGGL(gemm1_kernel, dim3(HID / 128, NT / 128, NE), dim3(256), 0, stream,
                     xb, w1t, b1, wgt, hw);
  hipLaunchKernelGGL(gemm2_kernel, dim3(DIM / 128, NT / 128, 1), dim3(256), 0, stream,
                     hw, w2t, b2, wgt, out);
}

// Round 2
// 355.038 us; speedup vs baseline: 1.1184x; 1.1184x over previous
//
#include <hip/hip_runtime.h>
#include <hip/hip_bf16.h>
#include <math.h>

#define DIM 1024
#define HID 2048
#define NE  4
#define NT  4096            // B*T tokens
#define KW  (NE*HID)        // 8192, GEMM2 K / Hw leading dim
#define KSPLIT 4
#define KCH (KW / KSPLIT)   // 2048 per split

typedef __attribute__((ext_vector_type(8))) short short8;
typedef __attribute__((ext_vector_type(4))) short short4v;
typedef __attribute__((ext_vector_type(4))) float floatx4;

// ---- helpers ----------------------------------------------------------------

__device__ __forceinline__ void async_cp16(const void* g, void* l) {
  __builtin_amdgcn_global_load_lds(
      (const __attribute__((address_space(1))) void*)g,
      (__attribute__((address_space(3))) void*)l, 16, 0, 0);
}

__device__ __forceinline__ short f2bf(float f) {
  union { float f; unsigned u; } x; x.f = f;
  unsigned r = x.u + 0x7fffu + ((x.u >> 16) & 1u);   // round-to-nearest-even
  return (short)(r >> 16);
}

// fast GELU (tanh form via sigmoid + v_exp/v_rcp); |err| ~2e-4 vs exact
__device__ __forceinline__ float gelu_fast(float v) {
  float u = 1.595769122f * (v + 0.044715f * v * v * v);
  return v * __builtin_amdgcn_rcpf(1.0f + __expf(-u));
}

// ---- router: weights = softmax(x @ Wr + br), fp32 exact ---------------------
__global__ void router_kernel(const float* __restrict__ x,
                              const float* __restrict__ Wr,
                              const float* __restrict__ br,
                              float* __restrict__ wgt) {
  const int wv = threadIdx.x >> 6, lane = threadIdx.x & 63;
  const int t = blockIdx.x * 4 + wv;
  const float* xr = x + (size_t)t * DIM;
  float a0 = 0.f, a1 = 0.f, a2 = 0.f, a3 = 0.f;
  for (int d = lane; d < DIM; d += 64) {
    float xv = xr[d];
    floatx4 wr = *(const floatx4*)&Wr[d * 4];
    a0 += xv * wr[0]; a1 += xv * wr[1]; a2 += xv * wr[2]; a3 += xv * wr[3];
  }
  #pragma unroll
  for (int off = 32; off; off >>= 1) {
    a0 += __shfl_down(a0, off);
    a1 += __shfl_down(a1, off);
    a2 += __shfl_down(a2, off);
    a3 += __shfl_down(a3, off);
  }
  a0 = __shfl(a0, 0); a1 = __shfl(a1, 0); a2 = __shfl(a2, 0); a3 = __shfl(a3, 0);
  float s0 = a0 + br[0], s1 = a1 + br[1], s2 = a2 + br[2], s3 = a3 + br[3];
  float m = fmaxf(fmaxf(s0, s1), fmaxf(s2, s3));
  float e0 = __expf(s0 - m), e1 = __expf(s1 - m), e2 = __expf(s2 - m), e3 = __expf(s3 - m);
  float inv = 1.f / (e0 + e1 + e2 + e3);
  float v = (lane == 0) ? e0 : (lane == 1) ? e1 : (lane == 2) ? e2 : e3;
  if (lane < 4) wgt[t * 4 + lane] = v * inv;
}

// ---- x: fp32 -> bf16, vectorized -------------------------------------------
__global__ void cvt_x(const float* __restrict__ x, short* __restrict__ xb) {
  int i = (blockIdx.x * 256 + threadIdx.x) * 4;
  floatx4 v = *(const floatx4*)&x[i];
  short4v o;
  o[0] = f2bf(v[0]); o[1] = f2bf(v[1]); o[2] = f2bf(v[2]); o[3] = f2bf(v[3]);
  *(short4v*)&xb[i] = o;
}

// ---- fp32 [z][R][C] -> bf16 [z][C][R] transpose+convert ---------------------
__global__ void transpose_cvt(const float* __restrict__ in, short* __restrict__ out,
                              int R, int C) {
  __shared__ float tile[32][33];
  const size_t zo = (size_t)blockIdx.z * R * C;
  in += zo; out += zo;
  const int tx = threadIdx.x, ty = threadIdx.y;   // 32 x 8
  const int c = blockIdx.x * 32 + tx;
  #pragma unroll
  for (int i = 0; i < 4; i++) {
    int r = blockIdx.y * 32 + ty + i * 8;
    tile[ty + i * 8][tx] = in[(size_t)r * C + c];
  }
  __syncthreads();
  const int r2 = blockIdx.y * 32 + tx;
  #pragma unroll
  for (int i = 0; i < 4; i++) {
    int c2 = blockIdx.x * 32 + ty + i * 8;
    out[(size_t)c2 * R + r2] = f2bf(tile[tx][ty + i * 8]);
  }
}

// ---- GEMM1: Hw[t][e*HID+h] = bf16( w[t][e] * gelu(x @ W1[e] + b1[e]) ) ------
__global__ __launch_bounds__(256, 2)
void gemm1_kernel(const short* __restrict__ xb, const short* __restrict__ w1t,
                  const float* __restrict__ b1, const float* __restrict__ wgt,
                  short* __restrict__ hw) {
  const int e  = blockIdx.z;
  const int m0 = blockIdx.y * 128;
  const int n0 = blockIdx.x * 128;
  const int tid = threadIdx.x;
  const int lane = tid & 63;
  const int wv = tid >> 6;
  const int wm = (wv >> 1) * 64, wn = (wv & 1) * 64;
  const int quad = lane >> 4, lrow = lane & 15;
  const int srow = tid >> 2;                       // staging row 0..63
  const int skof = ((tid ^ srow) & 3) * 8;         // XOR-swizzled global k-block
  const int sw = lrow & 3;                          // read-side swizzle key

  __shared__ __align__(16) short As[128 * 32];
  __shared__ __align__(16) short Bs[128 * 32];

  const short* Ap = xb;
  const short* Bp = w1t + (size_t)e * HID * DIM;

  floatx4 acc[4][4];
  #pragma unroll
  for (int i = 0; i < 4; i++)
    #pragma unroll
    for (int j = 0; j < 4; j++) acc[i][j] = (floatx4)0.f;

  for (int k0 = 0; k0 < DIM; k0 += 32) {
    __syncthreads();
    async_cp16(Ap + (size_t)(m0 + srow)      * DIM + k0 + skof, As + tid * 8);
    async_cp16(Ap + (size_t)(m0 + 64 + srow) * DIM + k0 + skof, As + 2048 + tid * 8);
    async_cp16(Bp + (size_t)(n0 + srow)      * DIM + k0 + skof, Bs + tid * 8);
    async_cp16(Bp + (size_t)(n0 + 64 + srow) * DIM + k0 + skof, Bs + 2048 + tid * 8);
    __syncthreads();
    short8 af[4], bf[4];
    #pragma unroll
    for (int i = 0; i < 4; i++)
      af[i] = *(const short8*)&As[(wm + i * 16 + lrow) * 32 + ((quad ^ sw) * 8)];
    #pragma unroll
    for (int j = 0; j < 4; j++)
      bf[j] = *(const short8*)&Bs[(wn + j * 16 + lrow) * 32 + ((quad ^ sw) * 8)];
    #pragma unroll
    for (int i = 0; i < 4; i++)
      #pragma unroll
      for (int j = 0; j < 4; j++)
        acc[i][j] = __builtin_amdgcn_mfma_f32_16x16x32_bf16(af[i], bf[j], acc[i][j], 0, 0, 0);
  }

  // epilogue: bias + fast gelu + router-weight fold + bf16 store
  #pragma unroll
  for (int i = 0; i < 4; i++) {
    const int rbase = m0 + wm + i * 16 + quad * 4;
    float wv4[4];
    #pragma unroll
    for (int r = 0; r < 4; r++) wv4[r] = wgt[(rbase + r) * NE + e];
    #pragma unroll
    for (int j = 0; j < 4; j++) {
      const int col = n0 + wn + j * 16 + lrow;          // h
      const float b = b1[e * HID + col];
      #pragma unroll
      for (int r = 0; r < 4; r++) {
        float v = acc[i][j][r] + b;
        hw[(size_t)(rbase + r) * KW + e * HID + col] = f2bf(wv4[r] * gelu_fast(v));
      }
    }
  }
}

// ---- GEMM2 (split-K): out[t][d] = Hw @ W2t^T + sum_e w[t][e]*b2[e][d] -------
// blockIdx.z = kz. kz==0 writes out (+weighted bias); kz>0 writes fp32 partial.
__global__ __launch_bounds__(256, 2)
void gemm2_kernel(const short* __restrict__ hw, const short* __restrict__ w2t,
                  const float* __restrict__ b2, const float* __restrict__ wgt,
                  float* __restrict__ out, float* __restrict__ part) {
  const int kz = blockIdx.z;
  const int m0 = blockIdx.y * 128;
  const int n0 = blockIdx.x * 128;
  const int tid = threadIdx.x;
  const int lane = tid & 63;
  const int wv = tid >> 6;
  const int wm = (wv >> 1) * 64, wn = (wv & 1) * 64;
  const int quad = lane >> 4, lrow = lane & 15;
  const int srow = tid >> 2;
  const int skof = ((tid ^ srow) & 3) * 8;
  const int sw = lrow & 3;

  __shared__ __align__(16) short As[128 * 32];
  __shared__ __align__(16) short Bs[128 * 32];

  floatx4 acc[4][4];
  #pragma unroll
  for (int i = 0; i < 4; i++)
    #pragma unroll
    for (int j = 0; j < 4; j++) acc[i][j] = (floatx4)0.f;

  const int kbeg = kz * KCH;
  for (int kk = 0; kk < KCH; kk += 32) {
    const int k0 = kbeg + kk;
    __syncthreads();
    async_cp16(hw  + (size_t)(m0 + srow)      * KW + k0 + skof, As + tid * 8);
    async_cp16(hw  + (size_t)(m0 + 64 + srow) * KW + k0 + skof, As + 2048 + tid * 8);
    async_cp16(w2t + (size_t)(n0 + srow)      * KW + k0 + skof, Bs + tid * 8);
    async_cp16(w2t + (size_t)(n0 + 64 + srow) * KW + k0 + skof, Bs + 2048 + tid * 8);
    __syncthreads();
    short8 af[4], bf[4];
    #pragma unroll
    for (int i = 0; i < 4; i++)
      af[i] = *(const short8*)&As[(wm + i * 16 + lrow) * 32 + ((quad ^ sw) * 8)];
    #pragma unroll
    for (int j = 0; j < 4; j++)
      bf[j] = *(const short8*)&Bs[(wn + j * 16 + lrow) * 32 + ((quad ^ sw) * 8)];
    #pragma unroll
    for (int i = 0; i < 4; i++)
      #pragma unroll
      for (int j = 0; j < 4; j++)
        acc[i][j] = __builtin_amdgcn_mfma_f32_16x16x32_bf16(af[i], bf[j], acc[i][j], 0, 0, 0);
  }

  if (kz == 0) {
    // + sum_e w[t][e] * b2[e][d], fp32 store to out
    #pragma unroll
    for (int i = 0; i < 4; i++) {
      const int rbase = m0 + wm + i * 16 + quad * 4;
      floatx4 wr[4];
      #pragma unroll
      for (int r = 0; r < 4; r++) wr[r] = *(const floatx4*)&wgt[(rbase + r) * NE];
      #pragma unroll
      for (int j = 0; j < 4; j++) {
        const int col = n0 + wn + j * 16 + lrow;
        float b2v[4];
        #pragma unroll
        for (int eI = 0; eI < 4; eI++) b2v[eI] = b2[eI * DIM + col];
        #pragma unroll
        for (int r = 0; r < 4; r++) {
          float bias = wr[r][0] * b2v[0] + wr[r][1] * b2v[1] +
                       wr[r][2] * b2v[2] + wr[r][3] * b2v[3];
          out[(size_t)(rbase + r) * DIM + col] = acc[i][j][r] + bias;
        }
      }
    }
  } else {
    float* p = part + (size_t)(kz - 1) * NT * DIM;
    #pragma unroll
    for (int i = 0; i < 4; i++) {
      const int rbase = m0 + wm + i * 16 + quad * 4;
      #pragma unroll
      for (int j = 0; j < 4; j++) {
        const int col = n0 + wn + j * 16 + lrow;
        #pragma unroll
        for (int r = 0; r < 4; r++)
          p[(size_t)(rbase + r) * DIM + col] = acc[i][j][r];
      }
    }
  }
}

// ---- reduce: out += p0 + p1 + p2 -------------------------------------------
__global__ void reduce_out(float* __restrict__ out, const float* __restrict__ part) {
  int i = (blockIdx.x * 256 + threadIdx.x) * 4;
  floatx4 v = *(const floatx4*)&out[i];
  floatx4 a = *(const floatx4*)&part[i];
  floatx4 b = *(const floatx4*)&part[i + NT * DIM];
  floatx4 c = *(const floatx4*)&part[i + 2 * NT * DIM];
  v = v + a + b + c;
  *(floatx4*)&out[i] = v;
}

// ---- launch -----------------------------------------------------------------

extern "C" void kernel_launch(void* const* d_in, const int* in_sizes, int n_in,
                              void* d_out, int out_size, void* d_ws, size_t ws_size,
                              hipStream_t stream) {
  const float* x  = (const float*)d_in[0];
  const float* W1 = (const float*)d_in[1];
  const float* b1 = (const float*)d_in[2];
  const float* W2 = (const float*)d_in[3];
  const float* b2 = (const float*)d_in[4];
  const float* Wr = (const float*)d_in[5];
  const float* br = (const float*)d_in[6];
  float* out = (float*)d_out;

  // layout (bytes):
  //   wgt   @ 0         64 KB   fp32 [NT][NE]
  //   w2t   @ 64K       16 MB   bf16 [DIM][KW]
  //   hw    @ ~16.1M    64 MB   bf16 [NT][KW]
  //   xb    @ ~80.1M     8 MB   bf16 [NT][DIM]     (dead after gemm1)
  //   w1t   @ ~88.5M    16 MB   bf16 [NE][HID][DIM](dead after gemm1)
  //   part  @ ~80.1M    48 MB   fp32 [3][NT][DIM]  (aliases xb+w1t+16M tail)
  char* ws = (char*)d_ws;
  float* wgt = (float*)(ws);
  short* w2t = (short*)(ws + 65536);
  short* hw  = (short*)(ws + 65536 + 16777216);
  short* xb  = (short*)(ws + 65536 + 16777216 + 67108864);
  short* w1t = (short*)(ws + 65536 + 16777216 + 67108864 + 8388608);
  float* part= (float*)(ws + 65536 + 16777216 + 67108864);   // aliases xb/w1t region

  hipLaunchKernelGGL(router_kernel, dim3(NT / 4), dim3(256), 0, stream, x, Wr, br, wgt);
  hipLaunchKernelGGL(cvt_x, dim3(NT * DIM / 1024), dim3(256), 0, stream, x, xb);
  hipLaunchKernelGGL(transpose_cvt, dim3(HID / 32, DIM / 32, NE), dim3(32, 8), 0, stream,
                     W1, w1t, DIM, HID);
  hipLaunchKernelGGL(transpose_cvt, dim3(DIM / 32, KW / 32, 1), dim3(32, 8), 0, stream,
                     W2, w2t, KW, DIM);
  hipLaunchKernelGGL(gemm1_kernel, dim3(HID / 128, NT / 128, NE), dim3(256), 0, stream,
                     xb, w1t, b1, wgt, hw);
  hipLaunchKernelGGL(gemm2_kernel, dim3(DIM / 128, NT / 128, KSPLIT), dim3(256), 0, stream,
                     hw, w2t, b2, wgt, out, part);
  hipLaunchKernelGGL(reduce_out, dim3(NT * DIM / 1024), dim3(256), 0, stream, out, part);
}

// Round 3
// 322.524 us; speedup vs baseline: 1.2312x; 1.1008x over previous
//
#include <hip/hip_runtime.h>
#include <hip/hip_bf16.h>
#include <math.h>

#define DIM 1024
#define HID 2048
#define NE  4
#define NT  4096            // B*T tokens
#define KW  (NE*HID)        // 8192, GEMM2 K / Hw leading dim
#define KSPLIT 4
#define KCH (KW / KSPLIT)   // 2048 per split

typedef __attribute__((ext_vector_type(8))) short short8;
typedef __attribute__((ext_vector_type(4))) short short4v;
typedef __attribute__((ext_vector_type(4))) float floatx4;

// ---- helpers ----------------------------------------------------------------

__device__ __forceinline__ void async_cp16(const void* g, void* l) {
  __builtin_amdgcn_global_load_lds(
      (const __attribute__((address_space(1))) void*)g,
      (__attribute__((address_space(3))) void*)l, 16, 0, 0);
}

__device__ __forceinline__ short f2bf(float f) {
  union { float f; unsigned u; } x; x.f = f;
  unsigned r = x.u + 0x7fffu + ((x.u >> 16) & 1u);   // round-to-nearest-even
  return (short)(r >> 16);
}

// fast GELU (tanh form via sigmoid + v_exp/v_rcp); |err| ~2e-4 vs exact
__device__ __forceinline__ float gelu_fast(float v) {
  float u = 1.595769122f * (v + 0.044715f * v * v * v);
  return v * __builtin_amdgcn_rcpf(1.0f + __expf(-u));
}

// ---- router: weights = softmax(x @ Wr + br), fp32 exact ---------------------
__global__ void router_kernel(const float* __restrict__ x,
                              const float* __restrict__ Wr,
                              const float* __restrict__ br,
                              float* __restrict__ wgt) {
  const int wv = threadIdx.x >> 6, lane = threadIdx.x & 63;
  const int t = blockIdx.x * 4 + wv;
  const float* xr = x + (size_t)t * DIM;
  float a0 = 0.f, a1 = 0.f, a2 = 0.f, a3 = 0.f;
  for (int d = lane; d < DIM; d += 64) {
    float xv = xr[d];
    floatx4 wr = *(const floatx4*)&Wr[d * 4];
    a0 += xv * wr[0]; a1 += xv * wr[1]; a2 += xv * wr[2]; a3 += xv * wr[3];
  }
  #pragma unroll
  for (int off = 32; off; off >>= 1) {
    a0 += __shfl_down(a0, off);
    a1 += __shfl_down(a1, off);
    a2 += __shfl_down(a2, off);
    a3 += __shfl_down(a3, off);
  }
  a0 = __shfl(a0, 0); a1 = __shfl(a1, 0); a2 = __shfl(a2, 0); a3 = __shfl(a3, 0);
  float s0 = a0 + br[0], s1 = a1 + br[1], s2 = a2 + br[2], s3 = a3 + br[3];
  float m = fmaxf(fmaxf(s0, s1), fmaxf(s2, s3));
  float e0 = __expf(s0 - m), e1 = __expf(s1 - m), e2 = __expf(s2 - m), e3 = __expf(s3 - m);
  float inv = 1.f / (e0 + e1 + e2 + e3);
  float v = (lane == 0) ? e0 : (lane == 1) ? e1 : (lane == 2) ? e2 : e3;
  if (lane < 4) wgt[t * 4 + lane] = v * inv;
}

// ---- x: fp32 -> bf16, vectorized -------------------------------------------
__global__ void cvt_x(const float* __restrict__ x, short* __restrict__ xb) {
  int i = (blockIdx.x * 256 + threadIdx.x) * 4;
  floatx4 v = *(const floatx4*)&x[i];
  short4v o;
  o[0] = f2bf(v[0]); o[1] = f2bf(v[1]); o[2] = f2bf(v[2]); o[3] = f2bf(v[3]);
  *(short4v*)&xb[i] = o;
}

// ---- fp32 [z][R][C] -> bf16 [z][C][R] transpose+convert ---------------------
__global__ void transpose_cvt(const float* __restrict__ in, short* __restrict__ out,
                              int R, int C) {
  __shared__ float tile[32][33];
  const size_t zo = (size_t)blockIdx.z * R * C;
  in += zo; out += zo;
  const int tx = threadIdx.x, ty = threadIdx.y;   // 32 x 8
  const int c = blockIdx.x * 32 + tx;
  #pragma unroll
  for (int i = 0; i < 4; i++) {
    int r = blockIdx.y * 32 + ty + i * 8;
    tile[ty + i * 8][tx] = in[(size_t)r * C + c];
  }
  __syncthreads();
  const int r2 = blockIdx.y * 32 + tx;
  #pragma unroll
  for (int i = 0; i < 4; i++) {
    int c2 = blockIdx.x * 32 + ty + i * 8;
    out[(size_t)c2 * R + r2] = f2bf(tile[tx][ty + i * 8]);
  }
}

// ============================================================================
// GEMM tiles: 128x128, BK=64 (LDS 2x16KB), bf16 16x16x32 MFMA, 4 waves.
// LDS layout: row stride 64 shorts (128 B = all 32 banks). The 8x16B k-slots
// of row r are stored permuted: slot position p holds k-block (p ^ (r&7)).
// Reads by 8 consecutive lanes (lrow 0..7) then hit 8 distinct bank-classes
// (slot mod 8 = kb ^ lrow) -> conflict-free ds_read_b128.
// Staging: call c, thread tid -> slot s=c*256+tid, row=s>>3, pos=s&7,
// global k-block = pos ^ (row&7); LDS dest = base + tid*16B (wave-uniform+lane).
// ============================================================================

// ---- GEMM1: Hw[t][e*HID+h] = bf16( w[t][e] * gelu(x @ W1[e] + b1[e]) ) ------
__global__ __launch_bounds__(256, 2)
void gemm1_kernel(const short* __restrict__ xb, const short* __restrict__ w1t,
                  const float* __restrict__ b1, const float* __restrict__ wgt,
                  short* __restrict__ hw) {
  const int e  = blockIdx.z;
  const int m0 = blockIdx.y * 128;
  const int n0 = blockIdx.x * 128;
  const int tid = threadIdx.x;
  const int lane = tid & 63;
  const int wv = tid >> 6;
  const int wm = (wv >> 1) * 64, wn = (wv & 1) * 64;
  const int quad = lane >> 4, lrow = lane & 15;
  const int sr  = tid >> 3;                        // staging row-in-call 0..31
  const int kof = ((tid & 7) ^ (sr & 7)) * 8;      // swizzled global k offset (elems)
  const int rkey = lrow & 7;                       // read-side swizzle key

  __shared__ __align__(16) short As[128 * 64];
  __shared__ __align__(16) short Bs[128 * 64];

  const short* Ap = xb;
  const short* Bp = w1t + (size_t)e * HID * DIM;

  floatx4 acc[4][4];
  #pragma unroll
  for (int i = 0; i < 4; i++)
    #pragma unroll
    for (int j = 0; j < 4; j++) acc[i][j] = (floatx4)0.f;

  for (int k0 = 0; k0 < DIM; k0 += 64) {
    __syncthreads();
    #pragma unroll
    for (int c = 0; c < 4; c++)
      async_cp16(Ap + (size_t)(m0 + c * 32 + sr) * DIM + k0 + kof,
                 As + (c * 256 + tid) * 8);
    #pragma unroll
    for (int c = 0; c < 4; c++)
      async_cp16(Bp + (size_t)(n0 + c * 32 + sr) * DIM + k0 + kof,
                 Bs + (c * 256 + tid) * 8);
    __syncthreads();
    #pragma unroll
    for (int kk = 0; kk < 2; kk++) {
      short8 af[4], bf[4];
      const int ko = ((kk * 4 + quad) ^ rkey) * 8;
      #pragma unroll
      for (int i = 0; i < 4; i++)
        af[i] = *(const short8*)&As[(wm + i * 16 + lrow) * 64 + ko];
      #pragma unroll
      for (int j = 0; j < 4; j++)
        bf[j] = *(const short8*)&Bs[(wn + j * 16 + lrow) * 64 + ko];
      #pragma unroll
      for (int i = 0; i < 4; i++)
        #pragma unroll
        for (int j = 0; j < 4; j++)
          acc[i][j] = __builtin_amdgcn_mfma_f32_16x16x32_bf16(af[i], bf[j], acc[i][j], 0, 0, 0);
    }
  }

  // epilogue: bias + fast gelu + router-weight fold + bf16 store
  #pragma unroll
  for (int i = 0; i < 4; i++) {
    const int rbase = m0 + wm + i * 16 + quad * 4;
    float wv4[4];
    #pragma unroll
    for (int r = 0; r < 4; r++) wv4[r] = wgt[(rbase + r) * NE + e];
    #pragma unroll
    for (int j = 0; j < 4; j++) {
      const int col = n0 + wn + j * 16 + lrow;          // h
      const float b = b1[e * HID + col];
      #pragma unroll
      for (int r = 0; r < 4; r++) {
        float v = acc[i][j][r] + b;
        hw[(size_t)(rbase + r) * KW + e * HID + col] = f2bf(wv4[r] * gelu_fast(v));
      }
    }
  }
}

// ---- GEMM2 (split-K): out[t][d] = Hw @ W2t^T + sum_e w[t][e]*b2[e][d] -------
__global__ __launch_bounds__(256, 2)
void gemm2_kernel(const short* __restrict__ hw, const short* __restrict__ w2t,
                  const float* __restrict__ b2, const float* __restrict__ wgt,
                  float* __restrict__ out, float* __restrict__ part) {
  const int kz = blockIdx.z;
  const int m0 = blockIdx.y * 128;
  const int n0 = blockIdx.x * 128;
  const int tid = threadIdx.x;
  const int lane = tid & 63;
  const int wv = tid >> 6;
  const int wm = (wv >> 1) * 64, wn = (wv & 1) * 64;
  const int quad = lane >> 4, lrow = lane & 15;
  const int sr  = tid >> 3;
  const int kof = ((tid & 7) ^ (sr & 7)) * 8;
  const int rkey = lrow & 7;

  __shared__ __align__(16) short As[128 * 64];
  __shared__ __align__(16) short Bs[128 * 64];

  floatx4 acc[4][4];
  #pragma unroll
  for (int i = 0; i < 4; i++)
    #pragma unroll
    for (int j = 0; j < 4; j++) acc[i][j] = (floatx4)0.f;

  const int kbeg = kz * KCH;
  for (int kk0 = 0; kk0 < KCH; kk0 += 64) {
    const int k0 = kbeg + kk0;
    __syncthreads();
    #pragma unroll
    for (int c = 0; c < 4; c++)
      async_cp16(hw + (size_t)(m0 + c * 32 + sr) * KW + k0 + kof,
                 As + (c * 256 + tid) * 8);
    #pragma unroll
    for (int c = 0; c < 4; c++)
      async_cp16(w2t + (size_t)(n0 + c * 32 + sr) * KW + k0 + kof,
                 Bs + (c * 256 + tid) * 8);
    __syncthreads();
    #pragma unroll
    for (int kk = 0; kk < 2; kk++) {
      short8 af[4], bf[4];
      const int ko = ((kk * 4 + quad) ^ rkey) * 8;
      #pragma unroll
      for (int i = 0; i < 4; i++)
        af[i] = *(const short8*)&As[(wm + i * 16 + lrow) * 64 + ko];
      #pragma unroll
      for (int j = 0; j < 4; j++)
        bf[j] = *(const short8*)&Bs[(wn + j * 16 + lrow) * 64 + ko];
      #pragma unroll
      for (int i = 0; i < 4; i++)
        #pragma unroll
        for (int j = 0; j < 4; j++)
          acc[i][j] = __builtin_amdgcn_mfma_f32_16x16x32_bf16(af[i], bf[j], acc[i][j], 0, 0, 0);
    }
  }

  if (kz == 0) {
    #pragma unroll
    for (int i = 0; i < 4; i++) {
      const int rbase = m0 + wm + i * 16 + quad * 4;
      floatx4 wr[4];
      #pragma unroll
      for (int r = 0; r < 4; r++) wr[r] = *(const floatx4*)&wgt[(rbase + r) * NE];
      #pragma unroll
      for (int j = 0; j < 4; j++) {
        const int col = n0 + wn + j * 16 + lrow;
        float b2v[4];
        #pragma unroll
        for (int eI = 0; eI < 4; eI++) b2v[eI] = b2[eI * DIM + col];
        #pragma unroll
        for (int r = 0; r < 4; r++) {
          float bias = wr[r][0] * b2v[0] + wr[r][1] * b2v[1] +
                       wr[r][2] * b2v[2] + wr[r][3] * b2v[3];
          out[(size_t)(rbase + r) * DIM + col] = acc[i][j][r] + bias;
        }
      }
    }
  } else {
    float* p = part + (size_t)(kz - 1) * NT * DIM;
    #pragma unroll
    for (int i = 0; i < 4; i++) {
      const int rbase = m0 + wm + i * 16 + quad * 4;
      #pragma unroll
      for (int j = 0; j < 4; j++) {
        const int col = n0 + wn + j * 16 + lrow;
        #pragma unroll
        for (int r = 0; r < 4; r++)
          p[(size_t)(rbase + r) * DIM + col] = acc[i][j][r];
      }
    }
  }
}

// ---- reduce: out += p0 + p1 + p2 -------------------------------------------
__global__ void reduce_out(float* __restrict__ out, const float* __restrict__ part) {
  int i = (blockIdx.x * 256 + threadIdx.x) * 4;
  floatx4 v = *(const floatx4*)&out[i];
  floatx4 a = *(const floatx4*)&part[i];
  floatx4 b = *(const floatx4*)&part[i + NT * DIM];
  floatx4 c = *(const floatx4*)&part[i + 2 * NT * DIM];
  v = v + a + b + c;
  *(floatx4*)&out[i] = v;
}

// ---- launch -----------------------------------------------------------------

extern "C" void kernel_launch(void* const* d_in, const int* in_sizes, int n_in,
                              void* d_out, int out_size, void* d_ws, size_t ws_size,
                              hipStream_t stream) {
  const float* x  = (const float*)d_in[0];
  const float* W1 = (const float*)d_in[1];
  const float* b1 = (const float*)d_in[2];
  const float* W2 = (const float*)d_in[3];
  const float* b2 = (const float*)d_in[4];
  const float* Wr = (const float*)d_in[5];
  const float* br = (const float*)d_in[6];
  float* out = (float*)d_out;

  // layout (bytes):
  //   wgt   @ 0         64 KB   fp32 [NT][NE]
  //   w2t   @ 64K       16 MB   bf16 [DIM][KW]
  //   hw    @ ~16.1M    64 MB   bf16 [NT][KW]
  //   xb    @ ~80.1M     8 MB   bf16 [NT][DIM]     (dead after gemm1)
  //   w1t   @ ~88.5M    16 MB   bf16 [NE][HID][DIM](dead after gemm1)
  //   part  @ ~80.1M    48 MB   fp32 [3][NT][DIM]  (aliases xb+w1t+16M tail)
  char* ws = (char*)d_ws;
  float* wgt = (float*)(ws);
  short* w2t = (short*)(ws + 65536);
  short* hw  = (short*)(ws + 65536 + 16777216);
  short* xb  = (short*)(ws + 65536 + 16777216 + 67108864);
  short* w1t = (short*)(ws + 65536 + 16777216 + 67108864 + 8388608);
  float* part= (float*)(ws + 65536 + 16777216 + 67108864);   // aliases xb/w1t region

  hipLaunchKernelGGL(router_kernel, dim3(NT / 4), dim3(256), 0, stream, x, Wr, br, wgt);
  hipLaunchKernelGGL(cvt_x, dim3(NT * DIM / 1024), dim3(256), 0, stream, x, xb);
  hipLaunchKernelGGL(transpose_cvt, dim3(HID / 32, DIM / 32, NE), dim3(32, 8), 0, stream,
                     W1, w1t, DIM, HID);
  hipLaunchKernelGGL(transpose_cvt, dim3(DIM / 32, KW / 32, 1), dim3(32, 8), 0, stream,
                     W2, w2t, KW, DIM);
  hipLaunchKernelGGL(gemm1_kernel, dim3(HID / 128, NT / 128, NE), dim3(256), 0, stream,
                     xb, w1t, b1, wgt, hw);
  hipLaunchKernelGGL(gemm2_kernel, dim3(DIM / 128, NT / 128, KSPLIT), dim3(256), 0, stream,
                     hw, w2t, b2, wgt, out, part);
  hipLaunchKernelGGL(reduce_out, dim3(NT * DIM / 1024), dim3(256), 0, stream, out, part);
}